// Round 3
// baseline (39.996 us; speedup 1.0000x reference)
//
#include <hip/hip_runtime.h>
#include <hip/hip_fp16.h>

#define NN 1024
#define HID 256
#define XD 128

typedef _Float16 h2 __attribute__((ext_vector_type(2)));
typedef _Float16 h4 __attribute__((ext_vector_type(4)));

// wsh (halves):
//   pxh [0, 262144)       tiled [jblk16][ko32][slot64][kl8]
//   pyB [262144, 524288)  tiled [iblk64][kq64][il16][kl4]  (b1 folded in)
//   w2h [524288, 524544)
// wsf (floats, at byte 1049600):
#define WSF_BYTE_OFF 1049600
#define F_C    0      // 1024 : c[j] = exp(b2 - ls[j])
#define F_PART 1024   // 1024 : per (block, khalf-pair) exp-sum partials
#define F_T0P  3072   // 256  : per-prep-block T0 partials
#define F_LSP  3328   // 256  : per-prep-block ls partials

__device__ __forceinline__ h2 relu2(h2 x) {
  h2 z = {(_Float16)0, (_Float16)0};
  return __builtin_elementwise_max(x, z);
}

__device__ __forceinline__ float dot2f(h2 a, h2 b, float c) {
  return __builtin_amdgcn_fdot2(a, b, c, false);
}

__global__ __launch_bounds__(512) void prep_kernel(
    const float* __restrict__ x, const float* __restrict__ y,
    const float* __restrict__ W1, const float* __restrict__ b1,
    const float* __restrict__ w2, const float* __restrict__ b2p,
    const float* __restrict__ wb, const float* __restrict__ bbp,
    _Float16* __restrict__ wsh, float* __restrict__ wsf)
{
  __shared__ float sx[4][128];
  __shared__ float sy[4][128];
  __shared__ float spy2[4][256];
  __shared__ float st0[4][4];
  __shared__ float sls[4];
  const int t = threadIdx.x;
  const int blk = blockIdx.x;
  const int r0 = blk * 4;

  if (t < 128) {
    const int rl = t >> 5, f = t & 31;
    *(float4*)&sx[rl][f * 4] = *(const float4*)(x + (r0 + rl) * XD + f * 4);
  } else if (t < 256) {
    const int t2 = t - 128, rl = t2 >> 5, f = t2 & 31;
    *(float4*)&sy[rl][f * 4] = *(const float4*)(y + (r0 + rl) * XD + f * 4);
  }
  __syncthreads();

  const int side = t >> 8;   // waves 0-3: px side, waves 4-7: py side
  const int k = t & 255;
  float ap[4] = {0.f, 0.f, 0.f, 0.f};
  const float* wrow = W1 + k * 256 + side * 128;
  const float (*sm)[128] = side ? sy : sx;
#pragma unroll 8
  for (int dq = 0; dq < 32; ++dq) {
    float4 wv = *(const float4*)(wrow + dq * 4);
#pragma unroll
    for (int r = 0; r < 4; ++r) {
      float4 sv = *(const float4*)&sm[r][dq * 4];
      ap[r] = fmaf(sv.x, wv.x, ap[r]);
      ap[r] = fmaf(sv.y, wv.y, ap[r]);
      ap[r] = fmaf(sv.z, wv.z, ap[r]);
      ap[r] = fmaf(sv.w, wv.w, ap[r]);
    }
  }

  if (side == 1) {
    const float b1k = b1[k];
    _Float16* pyB = wsh + 262144;
#pragma unroll
    for (int r = 0; r < 4; ++r) {
      ap[r] += b1k;
      spy2[r][k] = ap[r];
      const int i = r0 + r;
      pyB[(((i >> 4) * 64 + (k >> 2)) * 16 + (i & 15)) * 4 + (k & 3)] = (_Float16)ap[r];
    }
  } else {
#pragma unroll
    for (int r = 0; r < 4; ++r) {
      const int j = r0 + r;
      wsh[((j >> 6) * 32 + (k >> 3)) * 512 + (j & 63) * 8 + (k & 7)] = (_Float16)ap[r];
    }
  }
  __syncthreads();

  if (side == 0) {
    const float w2k = w2[k];
    const int wv = t >> 6, lane = t & 63;
#pragma unroll
    for (int r = 0; r < 4; ++r) {
      float v = fmaxf(ap[r] + spy2[r][k], 0.f) * w2k;
      for (int o = 32; o > 0; o >>= 1) v += __shfl_down(v, o);
      if (lane == 0) st0[wv][r] = v;
    }
  } else if ((t & 255) < 128) {
    const int t2 = t & 255;
    const int rl = t2 >> 5, f = t2 & 31;
    float p = 0.f;
#pragma unroll
    for (int l = 0; l < 4; ++l) p = fmaf(sy[rl][f * 4 + l], wb[f * 4 + l], p);
    for (int m = 16; m > 0; m >>= 1) p += __shfl_xor(p, m);
    if (f == 0) {
      const float lsv = p + bbp[0];
      sls[rl] = lsv;
      wsf[F_C + r0 + rl] = __expf(b2p[0] - lsv);
    }
  }
  __syncthreads();

  if (t == 0) {
    const float b2v = b2p[0];
    float t0s = 0.f, lss = 0.f;
#pragma unroll
    for (int r = 0; r < 4; ++r) {
      t0s += st0[0][r] + st0[1][r] + st0[2][r] + st0[3][r] + b2v;
      lss += sls[r];
    }
    wsf[F_T0P + blk] = t0s;
    wsf[F_LSP + blk] = lss;
  }
  if (blk == 0 && t < 128) {
    h2 wv2;
    wv2.x = (_Float16)w2[2 * t];
    wv2.y = (_Float16)w2[2 * t + 1];
    ((h2*)(wsh + 524288))[t] = wv2;
  }
}

// grid 512: blk = bi*16 + bj, bi in [0,32), bj in [0,16).
// Block tile: 64 j (lanes) x 32 i.  Wave w: isub = w&1 (16 i), khalf = w>>1.
__global__ __launch_bounds__(256) void main_kernel(
    const _Float16* __restrict__ wsh, float* __restrict__ wsf)
{
  __shared__ _Float16 spx[16384];   // 32 KB: px[bj], full K, [ko32][slot64][kl8]
  __shared__ _Float16 sw2[256];
  __shared__ float sComb[2][16][64]; // 8 KB k-half exchange
  const int t = threadIdx.x;
  const int lane = t & 63;
  const int w = __builtin_amdgcn_readfirstlane(t >> 6);
  const int blk = blockIdx.x;
  const int bi = blk >> 4, bj = blk & 15;

  {
    const float4* gx = (const float4*)(wsh + (size_t)bj * 16384);
    float4* lx = (float4*)spx;
#pragma unroll
    for (int it = 0; it < 8; ++it) lx[it * 256 + t] = gx[it * 256 + t];
    if (t < 32) ((float4*)sw2)[t] = ((const float4*)(wsh + 524288))[t];
  }
  __syncthreads();

  const int isub = w & 1, khalf = w >> 1;
  const int iblk = bi * 2 + isub;
  // pyB: per iblk 4096 halves = 512 uint4; khalf selects kq in [khalf*32, +32)
  const uint4* __restrict__ bB =
      (const uint4*)(wsh + 262144) + (size_t)iblk * 512 + (size_t)khalf * 256;

  float acc[16] = {0.f,0.f,0.f,0.f,0.f,0.f,0.f,0.f,
                   0.f,0.f,0.f,0.f,0.f,0.f,0.f,0.f};

#pragma unroll 4
  for (int q = 0; q < 32; ++q) {
    const int kq = khalf * 32 + q;           // 4-k step index, 0..63
    // A: lane's 4 k-values (j = bj*64+lane): one ds_read_b64
    h4 a4 = *(const h4*)(spx + (kq >> 1) * 512 + lane * 8 + (kq & 1) * 4);
    const h2* ap = (const h2*)&a4;
    // w2: uniform broadcast read
    h4 w4 = *(const h4*)(sw2 + kq * 4);
    const h2* wp = (const h2*)&w4;
    // B: 16 i x 4 k, wave-uniform -> scalar loads
    uint4 b[8];
#pragma unroll
    for (int r = 0; r < 8; ++r) b[r] = bB[q * 8 + r];
    const h2* bh = (const h2*)b;
#pragma unroll
    for (int a = 0; a < 16; ++a) {
      float s = acc[a];
      h2 u0 = relu2(ap[0] + bh[a * 2 + 0]);
      s = dot2f(u0, wp[0], s);
      h2 u1 = relu2(ap[1] + bh[a * 2 + 1]);
      s = dot2f(u1, wp[1], s);
      acc[a] = s;
    }
  }

  if (w >= 2) {
#pragma unroll
    for (int a = 0; a < 16; ++a) sComb[isub][a][lane] = acc[a];
  }
  __syncthreads();
  if (w < 2) {
    const float cj = wsf[F_C + bj * 64 + lane];
    float ts = 0.f;
#pragma unroll
    for (int a = 0; a < 16; ++a) ts += __expf(acc[a] + sComb[isub][a][lane]);
    ts *= cj;
    for (int o = 32; o > 0; o >>= 1) ts += __shfl_down(ts, o);
    if (lane == 0) wsf[F_PART + blk * 2 + w] = ts;
  }
}

__global__ __launch_bounds__(256) void fin_kernel(
    const float* __restrict__ wsf, float* __restrict__ out)
{
  __shared__ float sr[4][3];
  const int t = threadIdx.x;
  float4 ev = *(const float4*)(wsf + F_PART + t * 4);
  float e = ev.x + ev.y + ev.z + ev.w;
  float t0 = wsf[F_T0P + t];
  float ls = wsf[F_LSP + t];
  for (int o = 32; o > 0; o >>= 1) {
    e  += __shfl_down(e, o);
    t0 += __shfl_down(t0, o);
    ls += __shfl_down(ls, o);
  }
  if ((t & 63) == 0) {
    sr[t >> 6][0] = e;
    sr[t >> 6][1] = t0;
    sr[t >> 6][2] = ls;
  }
  __syncthreads();
  if (t == 0) {
    const float es  = sr[0][0] + sr[1][0] + sr[2][0] + sr[3][0];
    const float t0s = sr[0][1] + sr[1][1] + sr[2][1] + sr[3][1];
    const float lss = sr[0][2] + sr[1][2] + sr[2][2] + sr[3][2];
    out[0] = 1.0f + t0s * (1.0f / 1024.0f) - lss * (1.0f / 1024.0f)
                  - es * (1.0f / 1048576.0f);
  }
}

extern "C" void kernel_launch(void* const* d_in, const int* in_sizes, int n_in,
                              void* d_out, int out_size, void* d_ws, size_t ws_size,
                              hipStream_t stream) {
  const float* x  = (const float*)d_in[0];
  const float* y  = (const float*)d_in[1];
  const float* W1 = (const float*)d_in[2];
  const float* b1 = (const float*)d_in[3];
  const float* w2 = (const float*)d_in[4];
  const float* b2 = (const float*)d_in[5];
  const float* wb = (const float*)d_in[6];
  const float* bb = (const float*)d_in[7];
  _Float16* wsh = (_Float16*)d_ws;
  float* wsf = (float*)((char*)d_ws + WSF_BYTE_OFF);
  float* out = (float*)d_out;

  hipLaunchKernelGGL(prep_kernel, dim3(256), dim3(512), 0, stream,
                     x, y, W1, b1, w2, b2, wb, bb, wsh, wsf);
  hipLaunchKernelGGL(main_kernel, dim3(512), dim3(256), 0, stream, wsh, wsf);
  hipLaunchKernelGGL(fin_kernel, dim3(1), dim3(256), 0, stream, wsf, out);
}